// Round 1
// baseline (1523.503 us; speedup 1.0000x reference)
//
#include <hip/hip_runtime.h>
#include <cstdint>

#define DEVINL __device__ __forceinline__

typedef __attribute__((ext_vector_type(4))) float floatx4;
typedef __attribute__((ext_vector_type(8))) __bf16 bf16x8;
typedef __attribute__((ext_vector_type(8))) unsigned short ushortx8;
typedef __attribute__((ext_vector_type(4))) unsigned short ushortx4;

DEVINL unsigned short f2bf(float x) {  // RNE fp32 -> bf16 (finite inputs)
  unsigned int u = __float_as_uint(x);
  u += 0x7fffu + ((u >> 16) & 1u);
  return (unsigned short)(u >> 16);
}
DEVINL float bf2f(unsigned short u) { return __uint_as_float(((unsigned int)u) << 16); }

DEVINL void gload_lds16(const void* g, void* l) {
  __builtin_amdgcn_global_load_lds(
      (const __attribute__((address_space(1))) void*)g,
      (__attribute__((address_space(3))) void*)l, 16, 0, 0);
}

// ---------------------------------------------------------------------------
// Generic C[M x N] = A[M x K] @ Bt[N x K]^T  (+epilogue), bf16 MFMA 16x16x32.
// Tiles: BM=BN=128, BK=32. 256 threads = 4 waves in 2x2, each wave 64x64 (4x4
// MFMA tiles). Bt always bf16 staged via global_load_lds (16B). A either bf16
// (global_load_lds) or fp32 (VGPR load + RNE convert + ds_write).
// EPI==0: C[row*ldc + coloff + col] = acc + bias[col]
// EPI==1: attention-score epilogue: atomicAdd(scores[row],
//         sum_col tanh(q[row/L][col] + bk[col] + acc) * v[col])
// Fragment layouts (learn_hip m89/m91/m120 verified):
//   A: m=lane&15, k=(lane>>4)*8+j ; B: n=lane&15, k=(lane>>4)*8+j
//   C/D: col=lane&15, row=(lane>>4)*4+reg
// ---------------------------------------------------------------------------
template <int EPI, bool ABF16>
__global__ __launch_bounds__(256) void gemm_bt(
    const float* __restrict__ Af, const unsigned short* __restrict__ Ab, int lda,
    const unsigned short* __restrict__ Bt, int ldb, int K,
    float* __restrict__ C, int ldc, int coloff, const float* __restrict__ bias,
    const float* __restrict__ qv, const float* __restrict__ bkv,
    const float* __restrict__ vvec, float* __restrict__ scores, int Lrows, int Hdim)
{
  __shared__ __align__(16) unsigned short As[128 * 32];
  __shared__ __align__(16) unsigned short Bs[128 * 32];

  const int tid  = threadIdx.x;
  const int wave = tid >> 6;
  const int lane = tid & 63;
  const int qd   = lane >> 4;
  const int lm   = lane & 15;
  const int wr   = wave >> 1;
  const int wc   = wave & 1;

  const long n0 = (long)blockIdx.x * 128;
  const long m0 = (long)blockIdx.y * 128;

  floatx4 acc[4][4];
#pragma unroll
  for (int i = 0; i < 4; ++i)
#pragma unroll
    for (int j = 0; j < 4; ++j)
#pragma unroll
      for (int r = 0; r < 4; ++r) acc[i][j][r] = 0.0f;

  const int arow = tid >> 1;          // fp32 A staging: 2 threads/row
  const int acb  = (tid & 1) * 16;
  const int srow = lane >> 2;         // bf16 tile staging: 4 lanes/row
  const int skof = (lane & 3) * 8;

  const int nIter = K >> 5;
  for (int it = 0; it < nIter; ++it) {
    const int k0 = it << 5;
    {
      const unsigned short* bsrc = Bt + n0 * (size_t)ldb + k0;
#pragma unroll
      for (int q2 = 0; q2 < 2; ++q2) {
        const int rb = wave * 32 + q2 * 16;   // wave-uniform LDS base
        gload_lds16(bsrc + (size_t)(rb + srow) * ldb + skof, &Bs[rb * 32]);
      }
    }
    if (ABF16) {
      const unsigned short* asrc = Ab + m0 * (size_t)lda + k0;
#pragma unroll
      for (int q2 = 0; q2 < 2; ++q2) {
        const int rb = wave * 32 + q2 * 16;
        gload_lds16(asrc + (size_t)(rb + srow) * lda + skof, &As[rb * 32]);
      }
    } else {
      const float* ap = Af + (m0 + arow) * (size_t)lda + k0 + acb;
      floatx4 f0 = *(const floatx4*)(ap + 0);
      floatx4 f1 = *(const floatx4*)(ap + 4);
      floatx4 f2 = *(const floatx4*)(ap + 8);
      floatx4 f3 = *(const floatx4*)(ap + 12);
      ushortx8 u0, u1;
#pragma unroll
      for (int e = 0; e < 4; ++e) {
        u0[e]     = f2bf(f0[e]);
        u0[e + 4] = f2bf(f1[e]);
        u1[e]     = f2bf(f2[e]);
        u1[e + 4] = f2bf(f3[e]);
      }
      *(ushortx8*)&As[arow * 32 + acb]     = u0;
      *(ushortx8*)&As[arow * 32 + acb + 8] = u1;
    }
    __syncthreads();

    bf16x8 af[4], bfr[4];
#pragma unroll
    for (int i = 0; i < 4; ++i) {
      const int m = wr * 64 + i * 16 + lm;
      af[i] = *(const bf16x8*)&As[m * 32 + qd * 8];
    }
#pragma unroll
    for (int j = 0; j < 4; ++j) {
      const int n = wc * 64 + j * 16 + lm;
      bfr[j] = *(const bf16x8*)&Bs[n * 32 + qd * 8];
    }
#pragma unroll
    for (int i = 0; i < 4; ++i)
#pragma unroll
      for (int j = 0; j < 4; ++j)
        acc[i][j] = __builtin_amdgcn_mfma_f32_16x16x32_bf16(af[i], bfr[j], acc[i][j], 0, 0, 0);
    __syncthreads();
  }

  if (EPI == 0) {
#pragma unroll
    for (int j = 0; j < 4; ++j) {
      const long gc = n0 + wc * 64 + j * 16 + lm;
      const float bj = bias[gc];
#pragma unroll
      for (int i = 0; i < 4; ++i) {
        const long gr0 = m0 + wr * 64 + i * 16 + qd * 4;
#pragma unroll
        for (int r = 0; r < 4; ++r)
          C[(gr0 + r) * (size_t)ldc + coloff + gc] = acc[i][j][r] + bj;
      }
    }
  } else {
    float vj[4], bkj[4];
    long gcj[4];
#pragma unroll
    for (int j = 0; j < 4; ++j) {
      gcj[j] = n0 + wc * 64 + j * 16 + lm;
      vj[j]  = vvec[gcj[j]];
      bkj[j] = bkv[gcj[j]];
    }
#pragma unroll
    for (int i = 0; i < 4; ++i) {
#pragma unroll
      for (int r = 0; r < 4; ++r) {
        const long grow = m0 + wr * 64 + i * 16 + qd * 4 + r;
        const int brow = (int)(grow / Lrows);
        const float* qrow = qv + (size_t)brow * Hdim;
        float s = 0.0f;
#pragma unroll
        for (int j = 0; j < 4; ++j)
          s += tanhf(qrow[gcj[j]] + bkj[j] + acc[i][j][r]) * vj[j];
        // reduce the 16 lanes sharing this row (same lane>>4 group)
        s += __shfl_xor(s, 1, 64);
        s += __shfl_xor(s, 2, 64);
        s += __shfl_xor(s, 4, 64);
        s += __shfl_xor(s, 8, 64);
        if (lm == 0) atomicAdd(&scores[grow], s);
      }
    }
  }
}

// --------------------------- prep kernels ----------------------------------
__global__ void transpose_f32_bf16(const float* __restrict__ in,
                                   unsigned short* __restrict__ out, int R, int C) {
  __shared__ float tile[32][33];
  const int c0 = blockIdx.x * 32, r0 = blockIdx.y * 32;
  const int tx = threadIdx.x, ty = threadIdx.y;  // (32,8)
#pragma unroll
  for (int yy = 0; yy < 4; ++yy)
    tile[ty + 8 * yy][tx] = in[(size_t)(r0 + ty + 8 * yy) * C + c0 + tx];
  __syncthreads();
#pragma unroll
  for (int yy = 0; yy < 4; ++yy)
    out[(size_t)(c0 + ty + 8 * yy) * R + r0 + tx] = f2bf(tile[tx][ty + 8 * yy]);
}

__global__ void convert_bf16(const float* __restrict__ in,
                             unsigned short* __restrict__ out, int n4) {
  const int idx = blockIdx.x * blockDim.x + threadIdx.x;
  if (idx < n4) {
    floatx4 f = *(const floatx4*)(in + 4 * (size_t)idx);
    ushortx4 u;
#pragma unroll
    for (int e = 0; e < 4; ++e) u[e] = f2bf(f[e]);
    *(ushortx4*)(out + 4 * (size_t)idx) = u;
  }
}

__global__ void gather_emb(const int* __restrict__ inputs, const float* __restrict__ emb,
                           float* __restrict__ rnn_in, int E, int ldr) {
  const int b = blockIdx.x, t = threadIdx.x;
  const int row = inputs[b];
  for (int e = t; e < E; e += 256)
    rnn_in[(size_t)b * ldr + e] = emb[(size_t)row * E + e];
}

// --------------------- softmax over L + weighted key sum -------------------
template <bool KB16>
__global__ __launch_bounds__(256) void softmax_context(
    const float* __restrict__ scores, const float* __restrict__ bv,
    const float* __restrict__ keysf, const unsigned short* __restrict__ keys16,
    float* __restrict__ weights, float* __restrict__ context, int L, int K)
{
  __shared__ float w[256];
  __shared__ float red[8];
  const int b = blockIdx.x, t = threadIdx.x;
  const int wave = t >> 6;
  float s = (t < L) ? scores[(size_t)b * L + t] + bv[0] : -3.4e38f;
  float m = s;
  for (int o = 32; o > 0; o >>= 1) m = fmaxf(m, __shfl_xor(m, o, 64));
  if ((t & 63) == 0) red[wave] = m;
  __syncthreads();
  m = fmaxf(fmaxf(red[0], red[1]), fmaxf(red[2], red[3]));
  float e = (t < L) ? __expf(s - m) : 0.0f;
  float sum = e;
  for (int o = 32; o > 0; o >>= 1) sum += __shfl_xor(sum, o, 64);
  if ((t & 63) == 0) red[4 + wave] = sum;
  __syncthreads();
  sum = red[4] + red[5] + red[6] + red[7];
  const float wv = e / sum;
  w[t] = wv;
  if (t < L) weights[(size_t)b * L + t] = wv;
  __syncthreads();
  for (int c = 0; c < K; c += 256) {
    const int k = c + t;
    float acc = 0.0f;
    if (KB16) {
      const unsigned short* kb = keys16 + (size_t)b * L * K + k;
      for (int l = 0; l < L; ++l) acc += w[l] * bf2f(kb[(size_t)l * K]);
    } else {
      const float* kb = keysf + (size_t)b * L * K + k;
      for (int l = 0; l < L; ++l) acc += w[l] * kb[(size_t)l * K];
    }
    context[(size_t)b * K + k] = acc;
  }
}

// ------------------------------- GRU cell ----------------------------------
__global__ void gru_kernel(const float* __restrict__ gi, const float* __restrict__ gh,
                           const float* __restrict__ hidden, float* __restrict__ hnew, int H) {
  const int idx = blockIdx.x * blockDim.x + threadIdx.x;  // B*H
  const int b = idx / H, h = idx % H;
  const size_t base = (size_t)b * 3 * H;
  const float ir = gi[base + h], iz = gi[base + H + h], inn = gi[base + 2 * H + h];
  const float hr = gh[base + h], hz = gh[base + H + h], hn = gh[base + 2 * H + h];
  const float r = 1.0f / (1.0f + __expf(-(ir + hr)));
  const float z = 1.0f / (1.0f + __expf(-(iz + hz)));
  const float n = tanhf(inn + r * hn);
  const float hv = hidden[(size_t)b * H + h];
  hnew[(size_t)b * H + h] = (1.0f - z) * n + z * hv;
}

// ---------------------------------------------------------------------------
extern "C" void kernel_launch(void* const* d_in, const int* in_sizes, int n_in,
                              void* d_out, int out_size, void* d_ws, size_t ws_size,
                              hipStream_t stream) {
  constexpr int V = 32000, E = 512, H = 1024, KD = 2048, L = 196, B = 256;
  constexpr int G3 = 3 * H;   // 3072
  constexpr int EH = E + H;   // 1536

  const int*   inputs = (const int*)d_in[0];
  const float* hidden = (const float*)d_in[1];
  const float* keys   = (const float*)d_in[2];
  const float* emb    = (const float*)d_in[3];
  const float* Wq     = (const float*)d_in[4];
  const float* bq     = (const float*)d_in[5];
  const float* Wk     = (const float*)d_in[6];
  const float* bk     = (const float*)d_in[7];
  const float* vvec   = (const float*)d_in[8];
  const float* bv     = (const float*)d_in[9];
  const float* fc0_W  = (const float*)d_in[10];
  const float* fc0_b  = (const float*)d_in[11];
  const float* W_ih   = (const float*)d_in[12];
  const float* W_hh   = (const float*)d_in[13];
  const float* b_ih   = (const float*)d_in[14];
  const float* b_hh   = (const float*)d_in[15];
  const float* fc1_W  = (const float*)d_in[16];
  const float* fc1_b  = (const float*)d_in[17];

  float* logits  = (float*)d_out;
  float* hnew    = logits + (size_t)B * V;
  float* weights = hnew + (size_t)B * H;

  char* ws = (char*)d_ws;
  size_t off = 0;
  auto bump = [&off](size_t bytes) {
    size_t p = off;
    off += (bytes + 255) & ~(size_t)255;
    return p;
  };
  unsigned short* WqT   = (unsigned short*)(ws + bump((size_t)H * H * 2));
  unsigned short* WkT   = (unsigned short*)(ws + bump((size_t)H * KD * 2));
  unsigned short* fc0T  = (unsigned short*)(ws + bump((size_t)H * KD * 2));
  unsigned short* fc1T  = (unsigned short*)(ws + bump((size_t)V * H * 2));
  unsigned short* Wih16 = (unsigned short*)(ws + bump((size_t)G3 * EH * 2));
  unsigned short* Whh16 = (unsigned short*)(ws + bump((size_t)G3 * H * 2));
  float* qbuf    = (float*)(ws + bump((size_t)B * H * 4));
  float* scoresb = (float*)(ws + bump((size_t)B * L * 4));
  float* context = (float*)(ws + bump((size_t)B * KD * 4));
  float* rnn_in  = (float*)(ws + bump((size_t)B * EH * 4));
  float* gi      = (float*)(ws + bump((size_t)B * G3 * 4));
  float* gh      = (float*)(ws + bump((size_t)B * G3 * 4));
  unsigned short* keys16 = (unsigned short*)(ws + bump((size_t)B * L * KD * 2));
  const bool useK16 = (off <= ws_size);  // constant across calls -> graph-safe

  hipMemsetAsync(scoresb, 0, (size_t)B * L * 4, stream);

  const dim3 tb(32, 8);
  transpose_f32_bf16<<<dim3(H / 32, H / 32), tb, 0, stream>>>(Wq, WqT, H, H);
  transpose_f32_bf16<<<dim3(H / 32, KD / 32), tb, 0, stream>>>(Wk, WkT, KD, H);
  transpose_f32_bf16<<<dim3(H / 32, KD / 32), tb, 0, stream>>>(fc0_W, fc0T, KD, H);
  transpose_f32_bf16<<<dim3(V / 32, H / 32), tb, 0, stream>>>(fc1_W, fc1T, H, V);
  convert_bf16<<<(G3 * EH / 4 + 255) / 256, 256, 0, stream>>>(W_ih, Wih16, G3 * EH / 4);
  convert_bf16<<<(G3 * H / 4 + 255) / 256, 256, 0, stream>>>(W_hh, Whh16, G3 * H / 4);
  if (useK16) {
    const int n4 = B * L * KD / 4;
    convert_bf16<<<(n4 + 255) / 256, 256, 0, stream>>>(keys, keys16, n4);
  }

  gather_emb<<<B, 256, 0, stream>>>(inputs, emb, rnn_in, E, EH);

  // q = hidden @ Wq + bq
  gemm_bt<0, false><<<dim3(H / 128, B / 128), 256, 0, stream>>>(
      hidden, nullptr, H, WqT, H, H, qbuf, H, 0, bq,
      nullptr, nullptr, nullptr, nullptr, 0, 0);

  // scores[b*L+l] = tanh(q[b]+bk+keys[b,l]@Wk) . v   (the 210 GFLOP GEMM)
  if (useK16)
    gemm_bt<1, true><<<dim3(H / 128, (B * L) / 128), 256, 0, stream>>>(
        nullptr, keys16, KD, WkT, KD, KD, nullptr, 0, 0, nullptr,
        qbuf, bk, vvec, scoresb, L, H);
  else
    gemm_bt<1, false><<<dim3(H / 128, (B * L) / 128), 256, 0, stream>>>(
        keys, nullptr, KD, WkT, KD, KD, nullptr, 0, 0, nullptr,
        qbuf, bk, vvec, scoresb, L, H);

  if (useK16)
    softmax_context<true><<<B, 256, 0, stream>>>(scoresb, bv, nullptr, keys16,
                                                 weights, context, L, KD);
  else
    softmax_context<false><<<B, 256, 0, stream>>>(scoresb, bv, keys, nullptr,
                                                  weights, context, L, KD);

  // rnn_in[:, E:] = context @ fc0_W + fc0_b
  gemm_bt<0, false><<<dim3(H / 128, B / 128), 256, 0, stream>>>(
      context, nullptr, KD, fc0T, KD, KD, rnn_in, EH, E, fc0_b,
      nullptr, nullptr, nullptr, nullptr, 0, 0);

  // gi = rnn_in @ W_ih^T + b_ih   (W_ih already N x K)
  gemm_bt<0, false><<<dim3(G3 / 128, B / 128), 256, 0, stream>>>(
      rnn_in, nullptr, EH, Wih16, EH, EH, gi, G3, 0, b_ih,
      nullptr, nullptr, nullptr, nullptr, 0, 0);

  // gh = hidden @ W_hh^T + b_hh
  gemm_bt<0, false><<<dim3(G3 / 128, B / 128), 256, 0, stream>>>(
      hidden, nullptr, H, Whh16, H, H, gh, G3, 0, b_hh,
      nullptr, nullptr, nullptr, nullptr, 0, 0);

  gru_kernel<<<(B * H) / 256, 256, 0, stream>>>(gi, gh, hidden, hnew, H);

  // logits = h_new @ fc1_W + fc1_b
  gemm_bt<0, false><<<dim3(V / 128, B / 128), 256, 0, stream>>>(
      hnew, nullptr, H, fc1T, H, H, logits, V, 0, fc1_b,
      nullptr, nullptr, nullptr, nullptr, 0, 0);
}

// Round 2
// 1307.217 us; speedup vs baseline: 1.1655x; 1.1655x over previous
//
#include <hip/hip_runtime.h>
#include <cstdint>

#define DEVINL __device__ __forceinline__

typedef __attribute__((ext_vector_type(4))) float floatx4;
typedef __attribute__((ext_vector_type(8))) __bf16 bf16x8;
typedef __attribute__((ext_vector_type(8))) unsigned short ushortx8;
typedef __attribute__((ext_vector_type(4))) unsigned short ushortx4;

DEVINL unsigned short f2bf(float x) {  // RNE fp32 -> bf16 (finite inputs)
  unsigned int u = __float_as_uint(x);
  u += 0x7fffu + ((u >> 16) & 1u);
  return (unsigned short)(u >> 16);
}
DEVINL float bf2f(unsigned short u) { return __uint_as_float(((unsigned int)u) << 16); }

DEVINL void gload_lds16(const void* g, void* l) {
  __builtin_amdgcn_global_load_lds(
      (const __attribute__((address_space(1))) void*)g,
      (__attribute__((address_space(3))) void*)l, 16, 0, 0);
}

// ---------------------------------------------------------------------------
// C[M x N] = A[M x K] @ Bt[N x K]^T (+epilogue), bf16 MFMA 16x16x32.
// BM=BN=128, BK=32, 256 thr = 4 waves 2x2, wave = 64x64 (4x4 MFMA tiles).
// LDS tiles are stored with a 16B-chunk XOR swizzle: data chunk q of row m
// lives at slot q ^ ((m ^ (m>>2)) & 3).  This turns the 8-way bank conflict
// of the row-stride-64B ds_read_b128 fragment loads into 2-way (free, m136).
// global_load_lds lane l (fixed LDS dst = base + 16*l) therefore sources
// global chunk (l&3) ^ ((l>>2)&3) ^ (l>>4) of row rb + (l>>2).
// EPI==0: C[row*ldc+coloff+col] = acc + bias[col]
// EPI==1: scores epilogue: atomicAdd(scores[row], sum_col tanh(q+bk+acc)*v)
// EPI==2: split-K: atomicAdd(C[...], acc + (z==0 ? bias : 0)); C pre-zeroed
// XSWZ: remap blocks in 64-block chunks so the 8 bx sharing one A-tile get
// the same id%8 (same XCD under round-robin dispatch) -> A staged once/L2.
// ---------------------------------------------------------------------------
template <int EPI, bool ABF16, bool XSWZ>
__global__ __launch_bounds__(256) void gemm_bt(
    const float* __restrict__ Af, const unsigned short* __restrict__ Ab, int lda,
    const unsigned short* __restrict__ Bt, int ldb, int Kc,
    float* __restrict__ C, int ldc, int coloff, const float* __restrict__ bias,
    const float* __restrict__ qv, const float* __restrict__ bkv,
    const float* __restrict__ vvec, float* __restrict__ scores, int Lrows, int Hdim)
{
  __shared__ __align__(16) unsigned short As[128 * 32];
  __shared__ __align__(16) unsigned short Bs[128 * 32];

  const int tid  = threadIdx.x;
  const int wave = tid >> 6;
  const int lane = tid & 63;
  const int qd   = lane >> 4;
  const int lm   = lane & 15;
  const int wr   = wave >> 1;
  const int wc   = wave & 1;

  int bx = blockIdx.x, by = blockIdx.y;
  if (XSWZ) {  // 64-block super-chunks: 8 by x 8 bx, same-by blocks share id%8
    const int id = by * 8 + bx;
    const int c = id >> 6, r = id & 63;
    by = c * 8 + (r & 7);
    bx = r >> 3;
  }
  const long n0 = (long)bx * 128;
  const long m0 = (long)by * 128;
  const long k0base = (long)blockIdx.z * Kc;

  floatx4 acc[4][4];
#pragma unroll
  for (int i = 0; i < 4; ++i)
#pragma unroll
    for (int j = 0; j < 4; ++j)
#pragma unroll
      for (int r = 0; r < 4; ++r) acc[i][j][r] = 0.0f;

  // staging (global_load_lds): lane -> (row, swizzled source chunk)
  const int srow = lane >> 2;
  const int scg  = ((lane & 3) ^ ((lane >> 2) & 3) ^ (lane >> 4)) * 8;  // shorts
  // fp32 A staging: 2 threads/row, thread covers data chunks q0,q0+1
  const int arow = tid >> 1;
  const int q0   = (tid & 1) * 2;
  const int sA   = ((arow & 3) ^ ((arow >> 2) & 3));
  // fragment read swizzle: chunk = qd ^ ((lm ^ (lm>>2)) & 3)
  const int fsw  = (qd ^ ((lm ^ (lm >> 2)) & 3)) * 8;

  const int nIter = Kc >> 5;
  for (int it = 0; it < nIter; ++it) {
    const long k0 = k0base + ((long)it << 5);
    {
      const unsigned short* bsrc = Bt + n0 * (size_t)ldb + k0;
#pragma unroll
      for (int q2 = 0; q2 < 2; ++q2) {
        const int rb = wave * 32 + q2 * 16;   // wave-uniform LDS base
        gload_lds16(bsrc + (size_t)(rb + srow) * ldb + scg, &Bs[rb * 32]);
      }
    }
    if (ABF16) {
      const unsigned short* asrc = Ab + m0 * (size_t)lda + k0;
#pragma unroll
      for (int q2 = 0; q2 < 2; ++q2) {
        const int rb = wave * 32 + q2 * 16;
        gload_lds16(asrc + (size_t)(rb + srow) * lda + scg, &As[rb * 32]);
      }
    } else {
      const float* ap = Af + (m0 + arow) * (size_t)lda + k0 + q0 * 8;
      floatx4 f0 = *(const floatx4*)(ap + 0);
      floatx4 f1 = *(const floatx4*)(ap + 4);
      floatx4 f2 = *(const floatx4*)(ap + 8);
      floatx4 f3 = *(const floatx4*)(ap + 12);
      ushortx8 u0, u1;
#pragma unroll
      for (int e = 0; e < 4; ++e) {
        u0[e]     = f2bf(f0[e]);
        u0[e + 4] = f2bf(f1[e]);
        u1[e]     = f2bf(f2[e]);
        u1[e + 4] = f2bf(f3[e]);
      }
      *(ushortx8*)&As[arow * 32 + (q0 ^ sA) * 8]       = u0;
      *(ushortx8*)&As[arow * 32 + ((q0 + 1) ^ sA) * 8] = u1;
    }
    __syncthreads();

    bf16x8 af[4], bfr[4];
#pragma unroll
    for (int i = 0; i < 4; ++i) {
      const int m = wr * 64 + i * 16 + lm;
      af[i] = *(const bf16x8*)&As[m * 32 + fsw];
    }
#pragma unroll
    for (int j = 0; j < 4; ++j) {
      const int n = wc * 64 + j * 16 + lm;
      bfr[j] = *(const bf16x8*)&Bs[n * 32 + fsw];
    }
#pragma unroll
    for (int i = 0; i < 4; ++i)
#pragma unroll
      for (int j = 0; j < 4; ++j)
        acc[i][j] = __builtin_amdgcn_mfma_f32_16x16x32_bf16(af[i], bfr[j], acc[i][j], 0, 0, 0);
    __syncthreads();
  }

  if (EPI == 0) {
#pragma unroll
    for (int j = 0; j < 4; ++j) {
      const long gc = n0 + wc * 64 + j * 16 + lm;
      const float bj = bias[gc];
#pragma unroll
      for (int i = 0; i < 4; ++i) {
        const long gr0 = m0 + wr * 64 + i * 16 + qd * 4;
#pragma unroll
        for (int r = 0; r < 4; ++r)
          C[(gr0 + r) * (size_t)ldc + coloff + gc] = acc[i][j][r] + bj;
      }
    }
  } else if (EPI == 2) {
#pragma unroll
    for (int j = 0; j < 4; ++j) {
      const long gc = n0 + wc * 64 + j * 16 + lm;
      const float bj = (blockIdx.z == 0) ? bias[gc] : 0.0f;
#pragma unroll
      for (int i = 0; i < 4; ++i) {
        const long gr0 = m0 + wr * 64 + i * 16 + qd * 4;
#pragma unroll
        for (int r = 0; r < 4; ++r)
          atomicAdd(&C[(gr0 + r) * (size_t)ldc + coloff + gc], acc[i][j][r] + bj);
      }
    }
  } else {
    float vj[4], bkj[4];
    long gcj[4];
#pragma unroll
    for (int j = 0; j < 4; ++j) {
      gcj[j] = n0 + wc * 64 + j * 16 + lm;
      vj[j]  = vvec[gcj[j]];
      bkj[j] = bkv[gcj[j]];
    }
#pragma unroll
    for (int i = 0; i < 4; ++i) {
#pragma unroll
      for (int r = 0; r < 4; ++r) {
        const long grow = m0 + wr * 64 + i * 16 + qd * 4 + r;
        const int brow = (int)(grow / Lrows);
        const float* qrow = qv + (size_t)brow * Hdim;
        float s = 0.0f;
#pragma unroll
        for (int j = 0; j < 4; ++j)
          s += tanhf(qrow[gcj[j]] + bkj[j] + acc[i][j][r]) * vj[j];
        s += __shfl_xor(s, 1, 64);
        s += __shfl_xor(s, 2, 64);
        s += __shfl_xor(s, 4, 64);
        s += __shfl_xor(s, 8, 64);
        if (lm == 0) atomicAdd(&scores[grow], s);
      }
    }
  }
}

// --------------------------- prep kernels ----------------------------------
__global__ void transpose_f32_bf16(const float* __restrict__ in,
                                   unsigned short* __restrict__ out, int R, int C) {
  __shared__ float tile[32][33];
  const int c0 = blockIdx.x * 32, r0 = blockIdx.y * 32;
  const int tx = threadIdx.x, ty = threadIdx.y;  // (32,8)
#pragma unroll
  for (int yy = 0; yy < 4; ++yy)
    tile[ty + 8 * yy][tx] = in[(size_t)(r0 + ty + 8 * yy) * C + c0 + tx];
  __syncthreads();
#pragma unroll
  for (int yy = 0; yy < 4; ++yy)
    out[(size_t)(c0 + ty + 8 * yy) * R + r0 + tx] = f2bf(tile[tx][ty + 8 * yy]);
}

__global__ void convert_bf16(const float* __restrict__ in,
                             unsigned short* __restrict__ out, int n4) {
  const int idx = blockIdx.x * blockDim.x + threadIdx.x;
  if (idx < n4) {
    floatx4 f = *(const floatx4*)(in + 4 * (size_t)idx);
    ushortx4 u;
#pragma unroll
    for (int e = 0; e < 4; ++e) u[e] = f2bf(f[e]);
    *(ushortx4*)(out + 4 * (size_t)idx) = u;
  }
}

__global__ void gather_emb(const int* __restrict__ inputs, const float* __restrict__ emb,
                           float* __restrict__ rnn_in, int E, int ldr) {
  const int b = blockIdx.x, t = threadIdx.x;
  const int row = inputs[b];
  for (int e = t; e < E; e += 256)
    rnn_in[(size_t)b * ldr + e] = emb[(size_t)row * E + e];
}

// ----------------------------- softmax over L ------------------------------
__global__ __launch_bounds__(256) void softmax_w(
    const float* __restrict__ scores, const float* __restrict__ bv,
    float* __restrict__ weights, int L)
{
  __shared__ float red[8];
  const int b = blockIdx.x, t = threadIdx.x;
  const int wave = t >> 6;
  float s = (t < L) ? scores[(size_t)b * L + t] + bv[0] : -3.4e38f;
  float m = s;
  for (int o = 32; o > 0; o >>= 1) m = fmaxf(m, __shfl_xor(m, o, 64));
  if ((t & 63) == 0) red[wave] = m;
  __syncthreads();
  m = fmaxf(fmaxf(red[0], red[1]), fmaxf(red[2], red[3]));
  float e = (t < L) ? __expf(s - m) : 0.0f;
  float sum = e;
  for (int o = 32; o > 0; o >>= 1) sum += __shfl_xor(sum, o, 64);
  if ((t & 63) == 0) red[4 + wave] = sum;
  __syncthreads();
  sum = red[4] + red[5] + red[6] + red[7];
  if (t < L) weights[(size_t)b * L + t] = e / sum;
}

// ------------------- context[b,k] = sum_l w[b,l]*keys[b,l,k] ---------------
template <bool KB16>
__global__ __launch_bounds__(256) void context_k(
    const float* __restrict__ weights, const unsigned short* __restrict__ keys16,
    const float* __restrict__ keysf, float* __restrict__ context, int L, int K)
{
  __shared__ float w[256];
  const int b = blockIdx.x, t = threadIdx.x;
  if (t < L) w[t] = weights[(size_t)b * L + t];
  __syncthreads();
  const int col0 = blockIdx.y * 512 + t * 2;
  float a0 = 0.0f, a1 = 0.0f;
  if (KB16) {
    const unsigned short* kp = keys16 + (size_t)b * L * K + col0;
#pragma unroll 4
    for (int l = 0; l < L; ++l) {
      const unsigned int u = *(const unsigned int*)(kp + (size_t)l * K);
      a0 += w[l] * bf2f((unsigned short)(u & 0xffff));
      a1 += w[l] * bf2f((unsigned short)(u >> 16));
    }
  } else {
    const float* kp = keysf + (size_t)b * L * K + col0;
#pragma unroll 4
    for (int l = 0; l < L; ++l) {
      a0 += w[l] * kp[(size_t)l * K];
      a1 += w[l] * kp[(size_t)l * K + 1];
    }
  }
  context[(size_t)b * K + col0]     = a0;
  context[(size_t)b * K + col0 + 1] = a1;
}

// ------------------------------- GRU cell ----------------------------------
__global__ void gru_kernel(const float* __restrict__ gi, const float* __restrict__ gh,
                           const float* __restrict__ hidden, float* __restrict__ hnew, int H) {
  const int idx = blockIdx.x * blockDim.x + threadIdx.x;  // B*H
  const int b = idx / H, h = idx % H;
  const size_t base = (size_t)b * 3 * H;
  const float ir = gi[base + h], iz = gi[base + H + h], inn = gi[base + 2 * H + h];
  const float hr = gh[base + h], hz = gh[base + H + h], hn = gh[base + 2 * H + h];
  const float r = 1.0f / (1.0f + __expf(-(ir + hr)));
  const float z = 1.0f / (1.0f + __expf(-(iz + hz)));
  const float n = tanhf(inn + r * hn);
  const float hv = hidden[(size_t)b * H + h];
  hnew[(size_t)b * H + h] = (1.0f - z) * n + z * hv;
}

// ---------------------------------------------------------------------------
extern "C" void kernel_launch(void* const* d_in, const int* in_sizes, int n_in,
                              void* d_out, int out_size, void* d_ws, size_t ws_size,
                              hipStream_t stream) {
  constexpr int V = 32000, E = 512, H = 1024, KD = 2048, L = 196, B = 256;
  constexpr int G3 = 3 * H;   // 3072
  constexpr int EH = E + H;   // 1536

  const int*   inputs = (const int*)d_in[0];
  const float* hidden = (const float*)d_in[1];
  const float* keys   = (const float*)d_in[2];
  const float* emb    = (const float*)d_in[3];
  const float* Wq     = (const float*)d_in[4];
  const float* bq     = (const float*)d_in[5];
  const float* Wk     = (const float*)d_in[6];
  const float* bk     = (const float*)d_in[7];
  const float* vvec   = (const float*)d_in[8];
  const float* bv     = (const float*)d_in[9];
  const float* fc0_W  = (const float*)d_in[10];
  const float* fc0_b  = (const float*)d_in[11];
  const float* W_ih   = (const float*)d_in[12];
  const float* W_hh   = (const float*)d_in[13];
  const float* b_ih   = (const float*)d_in[14];
  const float* b_hh   = (const float*)d_in[15];
  const float* fc1_W  = (const float*)d_in[16];
  const float* fc1_b  = (const float*)d_in[17];

  float* logits  = (float*)d_out;
  float* hnew    = logits + (size_t)B * V;
  float* weights = hnew + (size_t)B * H;

  char* ws = (char*)d_ws;
  size_t off = 0;
  auto bump = [&off](size_t bytes) {
    size_t p = off;
    off += (bytes + 255) & ~(size_t)255;
    return p;
  };
  unsigned short* WqT   = (unsigned short*)(ws + bump((size_t)H * H * 2));
  unsigned short* WkT   = (unsigned short*)(ws + bump((size_t)H * KD * 2));
  unsigned short* fc0T  = (unsigned short*)(ws + bump((size_t)H * KD * 2));
  unsigned short* fc1T  = (unsigned short*)(ws + bump((size_t)V * H * 2));
  unsigned short* Wih16 = (unsigned short*)(ws + bump((size_t)G3 * EH * 2));
  unsigned short* Whh16 = (unsigned short*)(ws + bump((size_t)G3 * H * 2));
  float* qbuf    = (float*)(ws + bump((size_t)B * H * 4));
  float* scoresb = (float*)(ws + bump((size_t)B * L * 4));
  float* context = (float*)(ws + bump((size_t)B * KD * 4));
  float* rnn_in  = (float*)(ws + bump((size_t)B * EH * 4));
  float* gi      = (float*)(ws + bump((size_t)B * G3 * 4));
  float* gh      = (float*)(ws + bump((size_t)B * G3 * 4));
  unsigned short* keys16 = (unsigned short*)(ws + bump((size_t)B * L * KD * 2));
  const bool useK16 = (off <= ws_size);  // constant across calls -> graph-safe

  // split-K targets must start from zero (ws is re-poisoned before each call)
  hipMemsetAsync(scoresb, 0, (size_t)B * L * 4, stream);
  hipMemsetAsync(qbuf, 0, (size_t)B * H * 4, stream);
  hipMemsetAsync(rnn_in, 0, (size_t)B * EH * 4, stream);
  hipMemsetAsync(gi, 0, (size_t)B * G3 * 4, stream);
  hipMemsetAsync(gh, 0, (size_t)B * G3 * 4, stream);

  const dim3 tb(32, 8);
  transpose_f32_bf16<<<dim3(H / 32, H / 32), tb, 0, stream>>>(Wq, WqT, H, H);
  transpose_f32_bf16<<<dim3(H / 32, KD / 32), tb, 0, stream>>>(Wk, WkT, KD, H);
  transpose_f32_bf16<<<dim3(H / 32, KD / 32), tb, 0, stream>>>(fc0_W, fc0T, KD, H);
  transpose_f32_bf16<<<dim3(V / 32, H / 32), tb, 0, stream>>>(fc1_W, fc1T, H, V);
  convert_bf16<<<(G3 * EH / 4 + 255) / 256, 256, 0, stream>>>(W_ih, Wih16, G3 * EH / 4);
  convert_bf16<<<(G3 * H / 4 + 255) / 256, 256, 0, stream>>>(W_hh, Whh16, G3 * H / 4);
  if (useK16) {
    const int n4 = B * L * KD / 4;
    convert_bf16<<<(n4 + 255) / 256, 256, 0, stream>>>(keys, keys16, n4);
  }

  gather_emb<<<B, 256, 0, stream>>>(inputs, emb, rnn_in, E, EH);

  // q = hidden @ Wq + bq   (split-K x4 -> 64 blocks instead of 16)
  gemm_bt<2, false, false><<<dim3(H / 128, B / 128, 4), 256, 0, stream>>>(
      hidden, nullptr, H, WqT, H, H / 4, qbuf, H, 0, bq,
      nullptr, nullptr, nullptr, nullptr, 0, 0);

  // scores[b*L+l] = tanh(q[b]+bk+keys[b,l]@Wk) . v   (the 210 GFLOP GEMM)
  if (useK16)
    gemm_bt<1, true, true><<<dim3(H / 128, (B * L) / 128, 1), 256, 0, stream>>>(
        nullptr, keys16, KD, WkT, KD, KD, nullptr, 0, 0, nullptr,
        qbuf, bk, vvec, scoresb, L, H);
  else
    gemm_bt<1, false, true><<<dim3(H / 128, (B * L) / 128, 1), 256, 0, stream>>>(
        keys, nullptr, KD, WkT, KD, KD, nullptr, 0, 0, nullptr,
        qbuf, bk, vvec, scoresb, L, H);

  softmax_w<<<B, 256, 0, stream>>>(scoresb, bv, weights, L);

  if (useK16)
    context_k<true><<<dim3(B, KD / 512), 256, 0, stream>>>(weights, keys16, nullptr,
                                                           context, L, KD);
  else
    context_k<false><<<dim3(B, KD / 512), 256, 0, stream>>>(weights, nullptr, keys,
                                                            context, L, KD);

  // rnn_in[:, E:] = context @ fc0_W + fc0_b   (split-K x4)
  gemm_bt<2, false, false><<<dim3(H / 128, B / 128, 4), 256, 0, stream>>>(
      context, nullptr, KD, fc0T, KD, KD / 4, rnn_in, EH, E, fc0_b,
      nullptr, nullptr, nullptr, nullptr, 0, 0);

  // gi = rnn_in @ W_ih^T + b_ih   (split-K x4)
  gemm_bt<2, false, false><<<dim3(G3 / 128, B / 128, 4), 256, 0, stream>>>(
      rnn_in, nullptr, EH, Wih16, EH, EH / 4, gi, G3, 0, b_ih,
      nullptr, nullptr, nullptr, nullptr, 0, 0);

  // gh = hidden @ W_hh^T + b_hh   (split-K x4)
  gemm_bt<2, false, false><<<dim3(G3 / 128, B / 128, 4), 256, 0, stream>>>(
      hidden, nullptr, H, Whh16, H, H / 4, gh, G3, 0, b_hh,
      nullptr, nullptr, nullptr, nullptr, 0, 0);

  gru_kernel<<<(B * H) / 256, 256, 0, stream>>>(gi, gh, hidden, hnew, H);

  // logits = h_new @ fc1_W + fc1_b  (500 blocks, no split needed)
  gemm_bt<0, false, false><<<dim3(V / 128, B / 128, 1), 256, 0, stream>>>(
      hnew, nullptr, H, fc1T, H, H, logits, V, 0, fc1_b,
      nullptr, nullptr, nullptr, nullptr, 0, 0);
}